// Round 2
// baseline (320.106 us; speedup 1.0000x reference)
//
#include <hip/hip_runtime.h>
#include <hip/hip_bf16.h>
#include <math.h>

// Problem constants (fixed by reference)
#define N_NODES 4096
#define N_SUBS  1024
#define NFEAT   128
#define HIDDEN  512
#define NHEADS  8
#define DHEAD   64
#define CAP     128   // max neighbors/row. node: mean 42, sd 6.4 -> 128 is +13 sigma

// ---------------------------------------------------------------------------
// zero int buffer (avoid hipMemsetAsync capture-legality doubt)
// ---------------------------------------------------------------------------
__global__ void zero_i32(int* __restrict__ p, int n) {
    int i = blockIdx.x * blockDim.x + threadIdx.x;
    if (i < n) p[i] = 0;
}

// ---------------------------------------------------------------------------
// Edge extraction: dense adj[N][N] -> CSR-ish (cnt[row], nbr[row][CAP]).
// Grid-stride over float4s; row = idx>>logN (N power of 2).
// Neighbor ORDER is arbitrary (atomic slots) — softmax/sum order changes are
// within fp32 rounding noise vs the threshold.
// ---------------------------------------------------------------------------
__global__ __launch_bounds__(256) void extract_edges(const float4* __restrict__ adj4,
                                                     int n4_total, int logN,
                                                     int* __restrict__ cnt,
                                                     int* __restrict__ nbr) {
    const int stride = gridDim.x * blockDim.x;
    const int mask = (1 << logN) - 1;
    for (int idx = blockIdx.x * blockDim.x + threadIdx.x; idx < n4_total; idx += stride) {
        float4 v = adj4[idx];
        int base = idx << 2;
        int row = base >> logN;
        int col = base & mask;
        if (v.x > 0.0f) { int p = atomicAdd(cnt + row, 1); if (p < CAP) nbr[(row << 7) + p] = col; }
        if (v.y > 0.0f) { int p = atomicAdd(cnt + row, 1); if (p < CAP) nbr[(row << 7) + p] = col + 1; }
        if (v.z > 0.0f) { int p = atomicAdd(cnt + row, 1); if (p < CAP) nbr[(row << 7) + p] = col + 2; }
        if (v.w > 0.0f) { int p = atomicAdd(cnt + row, 1); if (p < CAP) nbr[(row << 7) + p] = col + 3; }
    }
}

// ---------------------------------------------------------------------------
// fp32 tiled GEMM v2: C[M,N] = A[M,K] @ B[K,N] (+bias). M,N %64==0, K%32==0.
// BK=32, register prefetch of next tile, padded LDS, float4 epilogue.
// ---------------------------------------------------------------------------
#define BM 64
#define BN 64
#define BK 32
__global__ __launch_bounds__(256) void gemm_f32(const float* __restrict__ A,
                                                const float* __restrict__ B,
                                                const float* __restrict__ bias,
                                                float* __restrict__ C,
                                                int M, int N, int K) {
    __shared__ float As[BK][BM + 4];
    __shared__ float Bs[BK][BN + 4];
    const int tid = threadIdx.x;
    const int bm = blockIdx.y * BM;
    const int bn = blockIdx.x * BN;
    const int tr = tid >> 4;          // 0..15
    const int tc = tid & 15;          // 0..15
    // A staging: thread loads rows am0, am0+32 at k-offset ak0 (float4 each)
    const int am0 = tid >> 3;         // 0..31
    const int ak0 = (tid & 7) * 4;    // 0..28
    // B staging: rows bk0, bk0+16 at col-offset bn0 (float4 each)
    const int bk0 = tid >> 4;         // 0..15
    const int bn0 = (tid & 15) * 4;   // 0..60
    const float* Ab = A + (size_t)bm * K;
    const float* Bb = B + bn;

    float4 pa0 = *(const float4*)&Ab[(size_t)am0 * K + ak0];
    float4 pa1 = *(const float4*)&Ab[(size_t)(am0 + 32) * K + ak0];
    float4 pb0 = *(const float4*)&Bb[(size_t)bk0 * N + bn0];
    float4 pb1 = *(const float4*)&Bb[(size_t)(bk0 + 16) * N + bn0];

    float acc[4][4] = {};
    for (int k0 = 0; k0 < K; k0 += BK) {
        As[ak0 + 0][am0] = pa0.x; As[ak0 + 1][am0] = pa0.y;
        As[ak0 + 2][am0] = pa0.z; As[ak0 + 3][am0] = pa0.w;
        As[ak0 + 0][am0 + 32] = pa1.x; As[ak0 + 1][am0 + 32] = pa1.y;
        As[ak0 + 2][am0 + 32] = pa1.z; As[ak0 + 3][am0 + 32] = pa1.w;
        *(float4*)&Bs[bk0][bn0] = pb0;
        *(float4*)&Bs[bk0 + 16][bn0] = pb1;
        __syncthreads();
        if (k0 + BK < K) {
            const int kn = k0 + BK;
            pa0 = *(const float4*)&Ab[(size_t)am0 * K + kn + ak0];
            pa1 = *(const float4*)&Ab[(size_t)(am0 + 32) * K + kn + ak0];
            pb0 = *(const float4*)&Bb[(size_t)(kn + bk0) * N + bn0];
            pb1 = *(const float4*)&Bb[(size_t)(kn + bk0 + 16) * N + bn0];
        }
#pragma unroll
        for (int k = 0; k < BK; k++) {
            const float4 a4 = *(const float4*)&As[k][tr * 4];
            const float4 b4 = *(const float4*)&Bs[k][tc * 4];
            float a[4] = {a4.x, a4.y, a4.z, a4.w};
            float b[4] = {b4.x, b4.y, b4.z, b4.w};
#pragma unroll
            for (int i = 0; i < 4; i++)
#pragma unroll
                for (int j = 0; j < 4; j++)
                    acc[i][j] += a[i] * b[j];
        }
        __syncthreads();
    }
#pragma unroll
    for (int i = 0; i < 4; i++) {
        const int m = bm + tr * 4 + i;
        float4 o;
        o.x = acc[i][0]; o.y = acc[i][1]; o.z = acc[i][2]; o.w = acc[i][3];
        if (bias) {
            const float4 bv = *(const float4*)&bias[bn + tc * 4];
            o.x += bv.x; o.y += bv.y; o.z += bv.z; o.w += bv.w;
        }
        *(float4*)&C[(size_t)m * N + bn + tc * 4] = o;
    }
}

// ---------------------------------------------------------------------------
// fs[h,n] = sum_d Wh[n, h*64+d]*asrc[h,d];  fd likewise with adst.
// ---------------------------------------------------------------------------
__global__ __launch_bounds__(512) void fsfd_kernel(const float* __restrict__ Wh,
                                                   const float* __restrict__ asrc,
                                                   const float* __restrict__ adst,
                                                   float* __restrict__ fs,
                                                   float* __restrict__ fd, int N) {
    const int n = blockIdx.x;
    const int tid = threadIdx.x;
    const int h = tid >> 6;
    const int d = tid & 63;
    float w = Wh[(size_t)n * HIDDEN + tid];
    float vs = w * asrc[h * DHEAD + d];
    float vd = w * adst[h * DHEAD + d];
#pragma unroll
    for (int off = 32; off >= 1; off >>= 1) {
        vs += __shfl_xor(vs, off, 64);
        vd += __shfl_xor(vd, off, 64);
    }
    if (d == 0) {
        fs[h * N + n] = vs;
        fd[h * N + n] = vd;
    }
}

// ---------------------------------------------------------------------------
// GAT aggregate from CSR: out[i,h,d] = elu( sum_k alpha[h,i,k]*Wh[nbr[k],h,d] )
// One block per row i; 512 threads = 8 head-waves of 64 lanes.
// ---------------------------------------------------------------------------
__global__ __launch_bounds__(512) void gat_agg(const float* __restrict__ Wh,
                                               const float* __restrict__ fs,
                                               const float* __restrict__ fd,
                                               const int* __restrict__ cnt,
                                               const int* __restrict__ nbr,
                                               float* __restrict__ out, int N) {
    __shared__ int snbr[CAP];
    __shared__ float ex[NHEADS][CAP];
    const int i = blockIdx.x;
    const int tid = threadIdx.x;
    int C = cnt[i];
    C = C < CAP ? C : CAP;
    for (int k = tid; k < C; k += 512) snbr[k] = nbr[(i << 7) + k];
    __syncthreads();
    const int h = tid >> 6;
    const int lane = tid & 63;
    const float fsi = fs[h * N + i];
    float m = -1e30f;
    for (int k = lane; k < C; k += 64) {
        float e = fsi + fd[h * N + snbr[k]];
        e = e > 0.0f ? e : 0.2f * e;
        ex[h][k] = e;
        m = fmaxf(m, e);
    }
#pragma unroll
    for (int off = 32; off >= 1; off >>= 1) m = fmaxf(m, __shfl_xor(m, off, 64));
    float ssum = 0.0f;
    for (int k = lane; k < C; k += 64) {
        float v = __expf(ex[h][k] - m);
        ex[h][k] = v;
        ssum += v;
    }
#pragma unroll
    for (int off = 32; off >= 1; off >>= 1) ssum += __shfl_xor(ssum, off, 64);
    __syncthreads();  // ex[] visible to all lanes of each head-wave
    const float inv = 1.0f / ssum;  // self-loop guarantees C>=1
    const float* __restrict__ Whh = Wh + h * DHEAD + lane;
    float acc = 0.0f;
    int k = 0;
    for (; k + 4 <= C; k += 4) {
        const int j0 = snbr[k], j1 = snbr[k + 1], j2 = snbr[k + 2], j3 = snbr[k + 3];
        const float w0 = Whh[(size_t)j0 * HIDDEN];
        const float w1 = Whh[(size_t)j1 * HIDDEN];
        const float w2 = Whh[(size_t)j2 * HIDDEN];
        const float w3 = Whh[(size_t)j3 * HIDDEN];
        acc += ex[h][k] * w0 + ex[h][k + 1] * w1 + ex[h][k + 2] * w2 + ex[h][k + 3] * w3;
    }
    for (; k < C; k++) acc += ex[h][k] * Whh[(size_t)snbr[k] * HIDDEN];
    acc *= inv;
    out[(size_t)i * HIDDEN + h * DHEAD + lane] = acc > 0.0f ? acc : __expf(acc) - 1.0f;
}

// ---------------------------------------------------------------------------
// Segment-mean pooling. seg_ids sorted. One block per substation.
// ---------------------------------------------------------------------------
__global__ __launch_bounds__(512) void pool_kernel(const float* __restrict__ hin,
                                                   const int* __restrict__ seg,
                                                   float* __restrict__ sout) {
    const int s = blockIdx.x;
    const int d = threadIdx.x;
    int lo = 0, hi = N_NODES;
    while (lo < hi) { int mid = (lo + hi) >> 1; if (seg[mid] < s) lo = mid + 1; else hi = mid; }
    const int start = lo;
    hi = N_NODES;
    while (lo < hi) { int mid = (lo + hi) >> 1; if (seg[mid] < s + 1) lo = mid + 1; else hi = mid; }
    const int end = lo;
    float acc = 0.0f;
    for (int r = start; r < end; r++) acc += hin[(size_t)r * HIDDEN + d];
    const int c = end - start;
    sout[(size_t)s * HIDDEN + d] = acc / (c > 0 ? (float)c : 1.0f);
}

// ---------------------------------------------------------------------------
extern "C" void kernel_launch(void* const* d_in, const int* in_sizes, int n_in,
                              void* d_out, int out_size, void* d_ws, size_t ws_size,
                              hipStream_t stream) {
    const float* x        = (const float*)d_in[0];
    const float* adj_node = (const float*)d_in[1];
    const float* adj_sub  = (const float*)d_in[2];
    const int*   seg_ids  = (const int*)d_in[3];
    const float* lin_w    = (const float*)d_in[4];
    const float* lin_b    = (const float*)d_in[5];
    // _stacked_gats bug: every layer reads the ORIGINAL h; only the LAST
    // layer's output survives. Use layer index 1 only.
    const float* node_W1    = (const float*)d_in[6]  + HIDDEN * HIDDEN;
    const float* node_asrc1 = (const float*)d_in[7]  + NHEADS * DHEAD;
    const float* node_adst1 = (const float*)d_in[8]  + NHEADS * DHEAD;
    const float* sub_W1     = (const float*)d_in[9]  + HIDDEN * HIDDEN;
    const float* sub_asrc1  = (const float*)d_in[10] + NHEADS * DHEAD;
    const float* sub_adst1  = (const float*)d_in[11] + NHEADS * DHEAD;
    float* out = (float*)d_out;

    // Workspace layout (~18.8 MB; R1 proved ws_size > 16.25 MB in use):
    char* ws = (char*)d_ws;
    float* bufA   = (float*)(ws);                                // 4096*512 f32 (8MB)
    float* bufB   = (float*)(ws + (size_t)8 * 1024 * 1024);      // 4096*512 f32 (8MB)
    float* fs_n   = (float*)(ws + (size_t)16 * 1024 * 1024);     // 8*4096
    float* fd_n   = fs_n + NHEADS * N_NODES;                     // 8*4096
    int*   cnt_n  = (int*)(fd_n + NHEADS * N_NODES);             // 4096
    int*   cnt_s  = cnt_n + N_NODES;                             // 1024
    int*   nbr_n  = cnt_s + N_SUBS;                              // 4096*128 (2MB)
    int*   nbr_s  = nbr_n + N_NODES * CAP;                       // 1024*128 (0.5MB)

    float* h0    = bufA;
    float* wh_n  = bufB;
    float* gatom = bufA;                                         // node GAT out (h0 dead)
    float* sp    = bufB;                                         // 1024*512 (wh_n dead)
    float* wh_s  = bufB + (size_t)N_SUBS * HIDDEN;
    float* fs_s  = bufB + (size_t)2 * N_SUBS * HIDDEN;
    float* fd_s  = fs_s + NHEADS * N_SUBS;

    // 0. zero edge counters
    zero_i32<<<(N_NODES + N_SUBS + 255) / 256, 256, 0, stream>>>(cnt_n, N_NODES + N_SUBS);
    // 1. extract edges (node: 64MB scan; sub: 4MB scan)
    extract_edges<<<2048, 256, 0, stream>>>((const float4*)adj_node,
                                            N_NODES * N_NODES / 4, 12, cnt_n, nbr_n);
    extract_edges<<<256, 256, 0, stream>>>((const float4*)adj_sub,
                                           N_SUBS * N_SUBS / 4, 10, cnt_s, nbr_s);
    // 2. h0 = x @ lin_w + lin_b   [4096,128]@[128,512]
    gemm_f32<<<dim3(HIDDEN / BN, N_NODES / BM), 256, 0, stream>>>(
        x, lin_w, lin_b, h0, N_NODES, HIDDEN, NFEAT);
    // 3. Wh_node = h0 @ node_W[1]  [4096,512]@[512,512]
    gemm_f32<<<dim3(HIDDEN / BN, N_NODES / BM), 256, 0, stream>>>(
        h0, node_W1, nullptr, wh_n, N_NODES, HIDDEN, HIDDEN);
    // 4. attention logits
    fsfd_kernel<<<N_NODES, 512, 0, stream>>>(wh_n, node_asrc1, node_adst1,
                                             fs_n, fd_n, N_NODES);
    // 5. node GAT aggregate (CSR)
    gat_agg<<<N_NODES, 512, 0, stream>>>(wh_n, fs_n, fd_n, cnt_n, nbr_n,
                                         gatom, N_NODES);
    // 6. segment-mean pool
    pool_kernel<<<N_SUBS, 512, 0, stream>>>(gatom, seg_ids, sp);
    // 7. Wh_sub = s @ sub_W[1]  [1024,512]@[512,512]
    gemm_f32<<<dim3(HIDDEN / BN, N_SUBS / BM), 256, 0, stream>>>(
        sp, sub_W1, nullptr, wh_s, N_SUBS, HIDDEN, HIDDEN);
    // 8. sub attention logits
    fsfd_kernel<<<N_SUBS, 512, 0, stream>>>(wh_s, sub_asrc1, sub_adst1,
                                            fs_s, fd_s, N_SUBS);
    // 9. sub GAT aggregate -> final output
    gat_agg<<<N_SUBS, 512, 0, stream>>>(wh_s, fs_s, fd_s, cnt_s, nbr_s,
                                        out, N_SUBS);
}

// Round 3
// 265.982 us; speedup vs baseline: 1.2035x; 1.2035x over previous
//
#include <hip/hip_runtime.h>
#include <hip/hip_bf16.h>
#include <math.h>

// Problem constants (fixed by reference)
#define N_NODES 4096
#define N_SUBS  1024
#define NFEAT   128
#define HIDDEN  512
#define NHEADS  8
#define DHEAD   64
#define CAP     128   // max neighbors/row. node: mean 42, sd 6.4 -> 128 is +13 sigma

// ---------------------------------------------------------------------------
// Ballot-based edge extraction: one WAVE per row, no atomics, ascending order.
// adj row is N floats (N multiple of 256 so every lane iteration is full).
// ---------------------------------------------------------------------------
__global__ __launch_bounds__(256) void extract_ballot(const float* __restrict__ adj,
                                                      int N,
                                                      int* __restrict__ cnt,
                                                      int* __restrict__ nbr) {
    const int w = threadIdx.x >> 6;            // wave in block
    const int lane = threadIdx.x & 63;
    const int row = blockIdx.x * 4 + w;
    const float4* rowp = (const float4*)(adj + (size_t)row * N);
    int* nrow = nbr + (row << 7);              // CAP = 128
    const int n4 = N >> 2;
    int c = 0;
    for (int c4 = lane; c4 < n4; c4 += 64) {
        const float4 v = rowp[c4];
        const int col = c4 << 2;
        const unsigned long long below = (1ull << lane) - 1ull;
        unsigned long long m;
        bool p;
        p = v.x > 0.0f; m = __ballot(p);
        if (p) { int q = c + __popcll(m & below); if (q < CAP) nrow[q] = col; }
        c += __popcll(m);
        p = v.y > 0.0f; m = __ballot(p);
        if (p) { int q = c + __popcll(m & below); if (q < CAP) nrow[q] = col + 1; }
        c += __popcll(m);
        p = v.z > 0.0f; m = __ballot(p);
        if (p) { int q = c + __popcll(m & below); if (q < CAP) nrow[q] = col + 2; }
        c += __popcll(m);
        p = v.w > 0.0f; m = __ballot(p);
        if (p) { int q = c + __popcll(m & below); if (q < CAP) nrow[q] = col + 3; }
        c += __popcll(m);
    }
    if (lane == 0) cnt[row] = c < CAP ? c : CAP;
}

// ---------------------------------------------------------------------------
// fp32 tiled GEMM v3: C[M,N] = A[M,K]@B[K,N] (+bias). BM=BN=64, BK=16, 4x4.
// Conflict-free-ish staging (2-way max = free). blockIdx.z = K-chunk for
// split-K (writes partials at C + z*M*N).
// ---------------------------------------------------------------------------
#define BM 64
#define BN 64
#define BK 16
__global__ __launch_bounds__(256) void gemm_f32(const float* __restrict__ A,
                                                const float* __restrict__ B,
                                                const float* __restrict__ bias,
                                                float* __restrict__ C,
                                                int M, int N, int K, int k_chunk) {
    __shared__ float As[BK][BM + 4];   // stride 68: k4 pairs 2-way = free
    __shared__ float Bs[BK][BN + 4];
    const int tid = threadIdx.x;
    const int bm = blockIdx.y * BM;
    const int bn = blockIdx.x * BN;
    const int k_start = blockIdx.z * k_chunk;
    const int k_end = (k_start + k_chunk) < K ? (k_start + k_chunk) : K;
    float* Cw = C + (size_t)blockIdx.z * M * N;
    const int tr = tid >> 4;           // 0..15
    const int tc = tid & 15;           // 0..15
    const int am = tid >> 2;           // 0..63  (A staging row)
    const int ak4 = (tid & 3) * 4;     // 0,4,8,12
    const int bk = tid >> 4;           // 0..15  (B staging k)
    const int bn0 = (tid & 15) * 4;    // 0..60
    float acc[4][4] = {};
    for (int k0 = k_start; k0 < k_end; k0 += BK) {
        const float4 va = *(const float4*)&A[(size_t)(bm + am) * K + k0 + ak4];
        const float4 vb = *(const float4*)&B[(size_t)(k0 + bk) * N + bn + bn0];
        As[ak4 + 0][am] = va.x;
        As[ak4 + 1][am] = va.y;
        As[ak4 + 2][am] = va.z;
        As[ak4 + 3][am] = va.w;
        *(float4*)&Bs[bk][bn0] = vb;
        __syncthreads();
#pragma unroll
        for (int k = 0; k < BK; k++) {
            const float4 a4 = *(const float4*)&As[k][tr * 4];
            const float4 b4 = *(const float4*)&Bs[k][tc * 4];
            const float a[4] = {a4.x, a4.y, a4.z, a4.w};
            const float b[4] = {b4.x, b4.y, b4.z, b4.w};
#pragma unroll
            for (int i = 0; i < 4; i++)
#pragma unroll
                for (int j = 0; j < 4; j++)
                    acc[i][j] += a[i] * b[j];
        }
        __syncthreads();
    }
#pragma unroll
    for (int i = 0; i < 4; i++) {
        const int m = bm + tr * 4 + i;
        float4 o = {acc[i][0], acc[i][1], acc[i][2], acc[i][3]};
        if (bias) {
            const float4 bv = *(const float4*)&bias[bn + tc * 4];
            o.x += bv.x; o.y += bv.y; o.z += bv.z; o.w += bv.w;
        }
        *(float4*)&Cw[(size_t)m * N + bn + tc * 4] = o;
    }
}

// Sum split-K partials: out[i] = sum_z part[z*len + i]
__global__ __launch_bounds__(256) void reduce_partials(const float* __restrict__ part,
                                                       float* __restrict__ outp,
                                                       int len, int nz) {
    int i = blockIdx.x * 256 + threadIdx.x;
    if (i < len) {
        float s = 0.0f;
        for (int z = 0; z < nz; z++) s += part[(size_t)z * len + i];
        outp[i] = s;
    }
}

// bias2[n] = sum_k lin_b[k] * W1[k,n]   (512x512, coalesced over n)
__global__ __launch_bounds__(256) void gemv_bias(const float* __restrict__ lin_b,
                                                 const float* __restrict__ W1,
                                                 float* __restrict__ bias2) {
    const int n = blockIdx.x * 256 + threadIdx.x;
    float s = 0.0f;
    for (int k = 0; k < HIDDEN; k += 4) {
        s += lin_b[k]     * W1[(size_t)k * HIDDEN + n];
        s += lin_b[k + 1] * W1[(size_t)(k + 1) * HIDDEN + n];
        s += lin_b[k + 2] * W1[(size_t)(k + 2) * HIDDEN + n];
        s += lin_b[k + 3] * W1[(size_t)(k + 3) * HIDDEN + n];
    }
    bias2[n] = s;
}

// ---------------------------------------------------------------------------
// fs[h,n] = sum_d Wh[n, h*64+d]*asrc[h,d];  fd likewise with adst.
// ---------------------------------------------------------------------------
__global__ __launch_bounds__(512) void fsfd_kernel(const float* __restrict__ Wh,
                                                   const float* __restrict__ asrc,
                                                   const float* __restrict__ adst,
                                                   float* __restrict__ fs,
                                                   float* __restrict__ fd, int N) {
    const int n = blockIdx.x;
    const int tid = threadIdx.x;
    const int h = tid >> 6;
    const int d = tid & 63;
    float w = Wh[(size_t)n * HIDDEN + tid];
    float vs = w * asrc[h * DHEAD + d];
    float vd = w * adst[h * DHEAD + d];
#pragma unroll
    for (int off = 32; off >= 1; off >>= 1) {
        vs += __shfl_xor(vs, off, 64);
        vd += __shfl_xor(vd, off, 64);
    }
    if (d == 0) {
        fs[h * N + n] = vs;
        fd[h * N + n] = vd;
    }
}

// ---------------------------------------------------------------------------
// GAT aggregate from CSR: out[i,h,d] = elu( sum_k alpha[h,i,k]*Wh[nbr[k],h,d] )
// One block per row i; 512 threads = 8 head-waves of 64 lanes.
// ---------------------------------------------------------------------------
__global__ __launch_bounds__(512) void gat_agg(const float* __restrict__ Wh,
                                               const float* __restrict__ fs,
                                               const float* __restrict__ fd,
                                               const int* __restrict__ cnt,
                                               const int* __restrict__ nbr,
                                               float* __restrict__ out, int N) {
    __shared__ int snbr[CAP];
    __shared__ float ex[NHEADS][CAP];
    const int i = blockIdx.x;
    const int tid = threadIdx.x;
    int C = cnt[i];
    C = C < CAP ? C : CAP;
    for (int k = tid; k < C; k += 512) snbr[k] = nbr[(i << 7) + k];
    __syncthreads();
    const int h = tid >> 6;
    const int lane = tid & 63;
    const float fsi = fs[h * N + i];
    float m = -1e30f;
    for (int k = lane; k < C; k += 64) {
        float e = fsi + fd[h * N + snbr[k]];
        e = e > 0.0f ? e : 0.2f * e;
        ex[h][k] = e;
        m = fmaxf(m, e);
    }
#pragma unroll
    for (int off = 32; off >= 1; off >>= 1) m = fmaxf(m, __shfl_xor(m, off, 64));
    float ssum = 0.0f;
    for (int k = lane; k < C; k += 64) {
        float v = __expf(ex[h][k] - m);
        ex[h][k] = v;
        ssum += v;
    }
#pragma unroll
    for (int off = 32; off >= 1; off >>= 1) ssum += __shfl_xor(ssum, off, 64);
    __syncthreads();
    const float inv = 1.0f / ssum;  // self-loop guarantees C>=1
    const float* __restrict__ Whh = Wh + h * DHEAD + lane;
    float acc = 0.0f;
    int k = 0;
    for (; k + 4 <= C; k += 4) {
        const int j0 = snbr[k], j1 = snbr[k + 1], j2 = snbr[k + 2], j3 = snbr[k + 3];
        const float w0 = Whh[(size_t)j0 * HIDDEN];
        const float w1 = Whh[(size_t)j1 * HIDDEN];
        const float w2 = Whh[(size_t)j2 * HIDDEN];
        const float w3 = Whh[(size_t)j3 * HIDDEN];
        acc += ex[h][k] * w0 + ex[h][k + 1] * w1 + ex[h][k + 2] * w2 + ex[h][k + 3] * w3;
    }
    for (; k < C; k++) acc += ex[h][k] * Whh[(size_t)snbr[k] * HIDDEN];
    acc *= inv;
    out[(size_t)i * HIDDEN + h * DHEAD + lane] = acc > 0.0f ? acc : __expf(acc) - 1.0f;
}

// ---------------------------------------------------------------------------
// Segment-mean pooling. seg_ids sorted. One block per substation.
// ---------------------------------------------------------------------------
__global__ __launch_bounds__(512) void pool_kernel(const float* __restrict__ hin,
                                                   const int* __restrict__ seg,
                                                   float* __restrict__ sout) {
    const int s = blockIdx.x;
    const int d = threadIdx.x;
    int lo = 0, hi = N_NODES;
    while (lo < hi) { int mid = (lo + hi) >> 1; if (seg[mid] < s) lo = mid + 1; else hi = mid; }
    const int start = lo;
    hi = N_NODES;
    while (lo < hi) { int mid = (lo + hi) >> 1; if (seg[mid] < s + 1) lo = mid + 1; else hi = mid; }
    const int end = lo;
    float acc = 0.0f;
    for (int r = start; r < end; r++) acc += hin[(size_t)r * HIDDEN + d];
    const int c = end - start;
    sout[(size_t)s * HIDDEN + d] = acc / (c > 0 ? (float)c : 1.0f);
}

// ---------------------------------------------------------------------------
extern "C" void kernel_launch(void* const* d_in, const int* in_sizes, int n_in,
                              void* d_out, int out_size, void* d_ws, size_t ws_size,
                              hipStream_t stream) {
    const float* x        = (const float*)d_in[0];
    const float* adj_node = (const float*)d_in[1];
    const float* adj_sub  = (const float*)d_in[2];
    const int*   seg_ids  = (const int*)d_in[3];
    const float* lin_w    = (const float*)d_in[4];
    const float* lin_b    = (const float*)d_in[5];
    // _stacked_gats bug: every layer reads the ORIGINAL h; only the LAST
    // layer's output survives. Use layer index 1 only.
    const float* node_W1    = (const float*)d_in[6]  + HIDDEN * HIDDEN;
    const float* node_asrc1 = (const float*)d_in[7]  + NHEADS * DHEAD;
    const float* node_adst1 = (const float*)d_in[8]  + NHEADS * DHEAD;
    const float* sub_W1     = (const float*)d_in[9]  + HIDDEN * HIDDEN;
    const float* sub_asrc1  = (const float*)d_in[10] + NHEADS * DHEAD;
    const float* sub_adst1  = (const float*)d_in[11] + NHEADS * DHEAD;
    float* out = (float*)d_out;

    // Workspace (~18.9 MB, same footprint class as R2 which ran fine):
    char* ws = (char*)d_ws;
    float* bufA  = (float*)(ws);                              // 8 MB
    float* bufB  = (float*)(ws + (size_t)8 * 1024 * 1024);    // 8 MB
    float* fs_n  = (float*)(ws + (size_t)16 * 1024 * 1024);   // 128 KB
    float* fd_n  = fs_n + NHEADS * N_NODES;                   // 128 KB
    float* fs_s  = fd_n + NHEADS * N_NODES;                   // 32 KB
    float* fd_s  = fs_s + NHEADS * N_SUBS;                    // 32 KB
    int*   cnt_n = (int*)(fd_s + NHEADS * N_SUBS);            // 16 KB
    int*   cnt_s = cnt_n + N_NODES;                           // 4 KB
    int*   nbr_n = cnt_s + N_SUBS;                            // 2 MB
    int*   nbr_s = nbr_n + N_NODES * CAP;                     // 512 KB

    // Phase-1 overlays in bufB (dead before gat_agg writes gatom there):
    float* Wpart = bufB;                                      // 8 * 128*512 (2 MB)
    float* Wfuse = bufB + 8 * NFEAT * HIDDEN;                 // 128*512 (256 KB)
    float* bias2 = Wfuse + NFEAT * HIDDEN;                    // 512
    // Main buffers:
    float* wh_n  = bufA;                                      // 4096*512
    float* gatom = bufB;                                      // 4096*512 (phase 2)
    float* sp    = bufA;                                      // 1024*512
    float* wh_s  = bufA + N_SUBS * HIDDEN;                    // 1024*512

    // 1-2. edge extraction (ballot compaction, no atomics)
    extract_ballot<<<N_NODES / 4, 256, 0, stream>>>(adj_node, N_NODES, cnt_n, nbr_n);
    extract_ballot<<<N_SUBS / 4, 256, 0, stream>>>(adj_sub, N_SUBS, cnt_s, nbr_s);
    // 3. Wfuse = lin_w @ node_W1  [128,512]@[512,512], split-K=8 partials
    gemm_f32<<<dim3(HIDDEN / BN, NFEAT / BM, 8), 256, 0, stream>>>(
        lin_w, node_W1, nullptr, Wpart, NFEAT, HIDDEN, HIDDEN, HIDDEN / 8);
    // 4. reduce partials -> Wfuse
    reduce_partials<<<(NFEAT * HIDDEN + 255) / 256, 256, 0, stream>>>(
        Wpart, Wfuse, NFEAT * HIDDEN, 8);
    // 5. bias2 = lin_b @ node_W1
    gemv_bias<<<HIDDEN / 256, 256, 0, stream>>>(lin_b, node_W1, bias2);
    // 6. Wh_node = x @ Wfuse + bias2   [4096,128]@[128,512]
    gemm_f32<<<dim3(HIDDEN / BN, N_NODES / BM, 1), 256, 0, stream>>>(
        x, Wfuse, bias2, wh_n, N_NODES, HIDDEN, NFEAT, NFEAT);
    // 7. node attention logits
    fsfd_kernel<<<N_NODES, 512, 0, stream>>>(wh_n, node_asrc1, node_adst1,
                                             fs_n, fd_n, N_NODES);
    // 8. node GAT aggregate -> gatom (bufB; Wfuse/Wpart dead now)
    gat_agg<<<N_NODES, 512, 0, stream>>>(wh_n, fs_n, fd_n, cnt_n, nbr_n,
                                         gatom, N_NODES);
    // 9. segment-mean pool -> sp (bufA; wh_n dead)
    pool_kernel<<<N_SUBS, 512, 0, stream>>>(gatom, seg_ids, sp);
    // 10. Wh_sub = sp @ sub_W1  [1024,512]@[512,512]
    gemm_f32<<<dim3(HIDDEN / BN, N_SUBS / BM, 1), 256, 0, stream>>>(
        sp, sub_W1, nullptr, wh_s, N_SUBS, HIDDEN, HIDDEN, HIDDEN);
    // 11. sub attention logits
    fsfd_kernel<<<N_SUBS, 512, 0, stream>>>(wh_s, sub_asrc1, sub_adst1,
                                            fs_s, fd_s, N_SUBS);
    // 12. sub GAT aggregate -> final output
    gat_agg<<<N_SUBS, 512, 0, stream>>>(wh_s, fs_s, fd_s, cnt_s, nbr_s,
                                        out, N_SUBS);
}

// Round 4
// 255.740 us; speedup vs baseline: 1.2517x; 1.0401x over previous
//
#include <hip/hip_runtime.h>
#include <hip/hip_bf16.h>
#include <math.h>

// Problem constants (fixed by reference)
#define N_NODES 4096
#define N_SUBS  1024
#define NFEAT   128
#define HIDDEN  512
#define NHEADS  8
#define DHEAD   64
#define CAP     128   // max neighbors/row (mean ~42, sd ~6.4; 128 = +13 sigma)
#define ROWG    4     // neighbor groups in gat_agg phase B

// ---------------------------------------------------------------------------
// Ballot-based edge extraction: one WAVE per row, no atomics, ascending order.
// ---------------------------------------------------------------------------
__global__ __launch_bounds__(256) void extract_ballot(const float* __restrict__ adj,
                                                      int N,
                                                      int* __restrict__ cnt,
                                                      int* __restrict__ nbr) {
    const int w = threadIdx.x >> 6;
    const int lane = threadIdx.x & 63;
    const int row = blockIdx.x * 4 + w;
    const float4* rowp = (const float4*)(adj + (size_t)row * N);
    int* nrow = nbr + (row << 7);
    const int n4 = N >> 2;
    int c = 0;
    const unsigned long long below = (1ull << lane) - 1ull;
    for (int c4 = lane; c4 < n4; c4 += 64) {
        const float4 v = rowp[c4];
        const int col = c4 << 2;
        unsigned long long m;
        bool p;
        p = v.x > 0.0f; m = __ballot(p);
        if (p) { int q = c + __popcll(m & below); if (q < CAP) nrow[q] = col; }
        c += __popcll(m);
        p = v.y > 0.0f; m = __ballot(p);
        if (p) { int q = c + __popcll(m & below); if (q < CAP) nrow[q] = col + 1; }
        c += __popcll(m);
        p = v.z > 0.0f; m = __ballot(p);
        if (p) { int q = c + __popcll(m & below); if (q < CAP) nrow[q] = col + 2; }
        c += __popcll(m);
        p = v.w > 0.0f; m = __ballot(p);
        if (p) { int q = c + __popcll(m & below); if (q < CAP) nrow[q] = col + 3; }
        c += __popcll(m);
    }
    if (lane == 0) cnt[row] = c < CAP ? c : CAP;
}

// ---------------------------------------------------------------------------
// fp32 tiled GEMM: C[M,N]=A[M,K]@B[K,N](+bias). BM=BN=64, BK=16, 4x4/thread.
// blockIdx.z = K-chunk (split-K partials at C + z*M*N).
// Optional fused attention-logit epilogue (asrc != nullptr): BN==DHEAD==64 so
// head h == blockIdx.x; fs[h*M+m] = dot(Whbiased[m, h*64..], asrc[h]).
// Requires gridDim.z == 1 when asrc != nullptr (needs full-K acc).
// ---------------------------------------------------------------------------
#define BM 64
#define BN 64
#define BK 16
__global__ __launch_bounds__(256) void gemm_f32(const float* __restrict__ A,
                                                const float* __restrict__ B,
                                                const float* __restrict__ bias,
                                                float* __restrict__ C,
                                                int M, int N, int K, int k_chunk,
                                                const float* __restrict__ asrc,
                                                const float* __restrict__ adst,
                                                float* __restrict__ fs,
                                                float* __restrict__ fd) {
    __shared__ float As[BK][BM + 4];
    __shared__ float Bs[BK][BN + 4];
    const int tid = threadIdx.x;
    const int bm = blockIdx.y * BM;
    const int bn = blockIdx.x * BN;
    const int k_start = blockIdx.z * k_chunk;
    const int k_end = (k_start + k_chunk) < K ? (k_start + k_chunk) : K;
    float* Cw = C + (size_t)blockIdx.z * M * N;
    const int tr = tid >> 4;
    const int tc = tid & 15;
    const int am = tid >> 2;
    const int ak4 = (tid & 3) * 4;
    const int bk = tid >> 4;
    const int bn0 = (tid & 15) * 4;
    float acc[4][4] = {};
    for (int k0 = k_start; k0 < k_end; k0 += BK) {
        const float4 va = *(const float4*)&A[(size_t)(bm + am) * K + k0 + ak4];
        const float4 vb = *(const float4*)&B[(size_t)(k0 + bk) * N + bn + bn0];
        As[ak4 + 0][am] = va.x;
        As[ak4 + 1][am] = va.y;
        As[ak4 + 2][am] = va.z;
        As[ak4 + 3][am] = va.w;
        *(float4*)&Bs[bk][bn0] = vb;
        __syncthreads();
#pragma unroll
        for (int k = 0; k < BK; k++) {
            const float4 a4 = *(const float4*)&As[k][tr * 4];
            const float4 b4 = *(const float4*)&Bs[k][tc * 4];
            const float a[4] = {a4.x, a4.y, a4.z, a4.w};
            const float b[4] = {b4.x, b4.y, b4.z, b4.w};
#pragma unroll
            for (int i = 0; i < 4; i++)
#pragma unroll
                for (int j = 0; j < 4; j++)
                    acc[i][j] += a[i] * b[j];
        }
        __syncthreads();
    }
    // epilogue: bias + store (keep biased values in acc for attention dot)
#pragma unroll
    for (int i = 0; i < 4; i++) {
        const int m = bm + tr * 4 + i;
        if (bias) {
            const float4 bv = *(const float4*)&bias[bn + tc * 4];
            acc[i][0] += bv.x; acc[i][1] += bv.y; acc[i][2] += bv.z; acc[i][3] += bv.w;
        }
        float4 o = {acc[i][0], acc[i][1], acc[i][2], acc[i][3]};
        *(float4*)&Cw[(size_t)m * N + bn + tc * 4] = o;
    }
    if (asrc) {
        const int h = blockIdx.x;                  // BN==DHEAD
        const float4 as4 = *(const float4*)&asrc[h * DHEAD + tc * 4];
        const float4 ad4 = *(const float4*)&adst[h * DHEAD + tc * 4];
#pragma unroll
        for (int i = 0; i < 4; i++) {
            float vs = acc[i][0] * as4.x + acc[i][1] * as4.y +
                       acc[i][2] * as4.z + acc[i][3] * as4.w;
            float vd = acc[i][0] * ad4.x + acc[i][1] * ad4.y +
                       acc[i][2] * ad4.z + acc[i][3] * ad4.w;
#pragma unroll
            for (int off = 1; off < 16; off <<= 1) {
                vs += __shfl_xor(vs, off, 64);
                vd += __shfl_xor(vd, off, 64);
            }
            if (tc == 0) {
                const int m = bm + tr * 4 + i;
                fs[h * M + m] = vs;
                fd[h * M + m] = vd;
            }
        }
    }
}

// Sum split-K partials
__global__ __launch_bounds__(256) void reduce_partials(const float* __restrict__ part,
                                                       float* __restrict__ outp,
                                                       int len, int nz) {
    int i = blockIdx.x * 256 + threadIdx.x;
    if (i < len) {
        float s = 0.0f;
        for (int z = 0; z < nz; z++) s += part[(size_t)z * len + i];
        outp[i] = s;
    }
}

// bias2[n] = sum_k lin_b[k] * W1[k,n]
__global__ __launch_bounds__(256) void gemv_bias(const float* __restrict__ lin_b,
                                                 const float* __restrict__ W1,
                                                 float* __restrict__ bias2) {
    const int n = blockIdx.x * 256 + threadIdx.x;
    float s = 0.0f;
    for (int k = 0; k < HIDDEN; k += 4) {
        s += lin_b[k]     * W1[(size_t)k * HIDDEN + n];
        s += lin_b[k + 1] * W1[(size_t)(k + 1) * HIDDEN + n];
        s += lin_b[k + 2] * W1[(size_t)(k + 2) * HIDDEN + n];
        s += lin_b[k + 3] * W1[(size_t)(k + 3) * HIDDEN + n];
    }
    bias2[n] = s;
}

// ---------------------------------------------------------------------------
// GAT aggregate v2. Phase A: per-head softmax (wave h, lanes over neighbors),
// weights normalized in place. Phase B: float4 gather — 128 threads cover one
// 512-float row (2 KB coalesced per neighbor), 4 neighbor groups in flight,
// x2 unrolled; cross-group reduce via LDS.
// ---------------------------------------------------------------------------
__global__ __launch_bounds__(512) void gat_agg(const float* __restrict__ Wh,
                                               const float* __restrict__ fs,
                                               const float* __restrict__ fd,
                                               const int* __restrict__ cnt,
                                               const int* __restrict__ nbr,
                                               float* __restrict__ out, int N) {
    __shared__ int snbr[CAP];
    __shared__ float ex[NHEADS][CAP + 1];     // +1: break 8-way bank alias
    __shared__ float sacc[ROWG][HIDDEN];      // 8 KB
    const int i = blockIdx.x;
    const int tid = threadIdx.x;
    int C = cnt[i];
    C = C < CAP ? C : CAP;
    for (int k = tid; k < C; k += 512) snbr[k] = nbr[(i << 7) + k];
    __syncthreads();
    // --- Phase A: softmax per head ---
    {
        const int h = tid >> 6;
        const int lane = tid & 63;
        const float fsi = fs[h * N + i];
        const float* __restrict__ fdh = fd + h * N;
        float m = -1e30f;
        for (int k = lane; k < C; k += 64) {
            float e = fsi + fdh[snbr[k]];
            e = e > 0.0f ? e : 0.2f * e;
            ex[h][k] = e;
            m = fmaxf(m, e);
        }
#pragma unroll
        for (int off = 32; off >= 1; off >>= 1) m = fmaxf(m, __shfl_xor(m, off, 64));
        float ssum = 0.0f;
        for (int k = lane; k < C; k += 64) {
            float v = __expf(ex[h][k] - m);
            ex[h][k] = v;
            ssum += v;
        }
#pragma unroll
        for (int off = 32; off >= 1; off >>= 1) ssum += __shfl_xor(ssum, off, 64);
        const float inv = 1.0f / ssum;        // self-loop: C>=1
        for (int k = lane; k < C; k += 64) ex[h][k] *= inv;
    }
    __syncthreads();
    // --- Phase B: float4 gather ---
    const int g = tid >> 7;                   // neighbor group 0..3
    const int t = tid & 127;                  // float4 slot within row
    const int hh = t >> 4;                    // head of this slot
    float4 acc = {0.f, 0.f, 0.f, 0.f};
    int k = g;
    for (; k + ROWG < C; k += 2 * ROWG) {
        const int j0 = snbr[k];
        const int j1 = snbr[k + ROWG];
        const float a0 = ex[hh][k];
        const float a1 = ex[hh][k + ROWG];
        const float4 w0 = *(const float4*)&Wh[(size_t)j0 * HIDDEN + 4 * t];
        const float4 w1 = *(const float4*)&Wh[(size_t)j1 * HIDDEN + 4 * t];
        acc.x += a0 * w0.x + a1 * w1.x;
        acc.y += a0 * w0.y + a1 * w1.y;
        acc.z += a0 * w0.z + a1 * w1.z;
        acc.w += a0 * w0.w + a1 * w1.w;
    }
    if (k < C) {
        const int j0 = snbr[k];
        const float a0 = ex[hh][k];
        const float4 w0 = *(const float4*)&Wh[(size_t)j0 * HIDDEN + 4 * t];
        acc.x += a0 * w0.x; acc.y += a0 * w0.y;
        acc.z += a0 * w0.z; acc.w += a0 * w0.w;
    }
    *(float4*)&sacc[g][4 * t] = acc;
    __syncthreads();
    if (g == 0) {
        float4 r = acc;
#pragma unroll
        for (int gg = 1; gg < ROWG; gg++) {
            const float4 o = *(const float4*)&sacc[gg][4 * t];
            r.x += o.x; r.y += o.y; r.z += o.z; r.w += o.w;
        }
        r.x = r.x > 0.0f ? r.x : __expf(r.x) - 1.0f;
        r.y = r.y > 0.0f ? r.y : __expf(r.y) - 1.0f;
        r.z = r.z > 0.0f ? r.z : __expf(r.z) - 1.0f;
        r.w = r.w > 0.0f ? r.w : __expf(r.w) - 1.0f;
        *(float4*)&out[(size_t)i * HIDDEN + 4 * t] = r;
    }
}

// ---------------------------------------------------------------------------
// Segment-mean pooling. seg_ids sorted. One block per substation.
// ---------------------------------------------------------------------------
__global__ __launch_bounds__(512) void pool_kernel(const float* __restrict__ hin,
                                                   const int* __restrict__ seg,
                                                   float* __restrict__ sout) {
    const int s = blockIdx.x;
    const int d = threadIdx.x;
    int lo = 0, hi = N_NODES;
    while (lo < hi) { int mid = (lo + hi) >> 1; if (seg[mid] < s) lo = mid + 1; else hi = mid; }
    const int start = lo;
    hi = N_NODES;
    while (lo < hi) { int mid = (lo + hi) >> 1; if (seg[mid] < s + 1) lo = mid + 1; else hi = mid; }
    const int end = lo;
    float acc = 0.0f;
    for (int r = start; r < end; r++) acc += hin[(size_t)r * HIDDEN + d];
    const int c = end - start;
    sout[(size_t)s * HIDDEN + d] = acc / (c > 0 ? (float)c : 1.0f);
}

// ---------------------------------------------------------------------------
extern "C" void kernel_launch(void* const* d_in, const int* in_sizes, int n_in,
                              void* d_out, int out_size, void* d_ws, size_t ws_size,
                              hipStream_t stream) {
    const float* x        = (const float*)d_in[0];
    const float* adj_node = (const float*)d_in[1];
    const float* adj_sub  = (const float*)d_in[2];
    const int*   seg_ids  = (const int*)d_in[3];
    const float* lin_w    = (const float*)d_in[4];
    const float* lin_b    = (const float*)d_in[5];
    // _stacked_gats bug: every layer reads the ORIGINAL h; only the LAST
    // layer's output survives. Use layer index 1 only.
    const float* node_W1    = (const float*)d_in[6]  + HIDDEN * HIDDEN;
    const float* node_asrc1 = (const float*)d_in[7]  + NHEADS * DHEAD;
    const float* node_adst1 = (const float*)d_in[8]  + NHEADS * DHEAD;
    const float* sub_W1     = (const float*)d_in[9]  + HIDDEN * HIDDEN;
    const float* sub_asrc1  = (const float*)d_in[10] + NHEADS * DHEAD;
    const float* sub_adst1  = (const float*)d_in[11] + NHEADS * DHEAD;
    float* out = (float*)d_out;

    char* ws = (char*)d_ws;
    float* bufA  = (float*)(ws);                              // 8 MB
    float* bufB  = (float*)(ws + (size_t)8 * 1024 * 1024);    // 8 MB
    float* fs_n  = (float*)(ws + (size_t)16 * 1024 * 1024);
    float* fd_n  = fs_n + NHEADS * N_NODES;
    float* fs_s  = fd_n + NHEADS * N_NODES;
    float* fd_s  = fs_s + NHEADS * N_SUBS;
    int*   cnt_n = (int*)(fd_s + NHEADS * N_SUBS);
    int*   cnt_s = cnt_n + N_NODES;
    int*   nbr_n = cnt_s + N_SUBS;                            // 2 MB
    int*   nbr_s = nbr_n + N_NODES * CAP;                     // 512 KB

    // Phase-1 overlays in bufB (dead before gat_agg writes gatom there):
    float* Wpart = bufB;                                      // 8*128*512 (2 MB)
    float* Wfuse = bufB + 8 * NFEAT * HIDDEN;                 // 256 KB
    float* bias2 = Wfuse + NFEAT * HIDDEN;
    float* wh_n  = bufA;
    float* gatom = bufB;
    float* sp    = bufA;                                      // after wh_n dead
    float* wh_s  = bufA + N_SUBS * HIDDEN;

    // 1-2. edge extraction
    extract_ballot<<<N_NODES / 4, 256, 0, stream>>>(adj_node, N_NODES, cnt_n, nbr_n);
    extract_ballot<<<N_SUBS / 4, 256, 0, stream>>>(adj_sub, N_SUBS, cnt_s, nbr_s);
    // 3. Wfuse = lin_w @ node_W1  (split-K=8)
    gemm_f32<<<dim3(HIDDEN / BN, NFEAT / BM, 8), 256, 0, stream>>>(
        lin_w, node_W1, nullptr, Wpart, NFEAT, HIDDEN, HIDDEN, HIDDEN / 8,
        nullptr, nullptr, nullptr, nullptr);
    // 4. reduce partials
    reduce_partials<<<(NFEAT * HIDDEN + 255) / 256, 256, 0, stream>>>(
        Wpart, Wfuse, NFEAT * HIDDEN, 8);
    // 5. bias2 = lin_b @ node_W1
    gemv_bias<<<HIDDEN / 256, 256, 0, stream>>>(lin_b, node_W1, bias2);
    // 6. wh_n = x @ Wfuse + bias2, fused fs/fd epilogue
    gemm_f32<<<dim3(HIDDEN / BN, N_NODES / BM, 1), 256, 0, stream>>>(
        x, Wfuse, bias2, wh_n, N_NODES, HIDDEN, NFEAT, NFEAT,
        node_asrc1, node_adst1, fs_n, fd_n);
    // 7. node GAT aggregate -> gatom
    gat_agg<<<N_NODES, 512, 0, stream>>>(wh_n, fs_n, fd_n, cnt_n, nbr_n,
                                         gatom, N_NODES);
    // 8. segment-mean pool -> sp
    pool_kernel<<<N_SUBS, 512, 0, stream>>>(gatom, seg_ids, sp);
    // 9. wh_s = sp @ sub_W1, fused fs/fd epilogue
    gemm_f32<<<dim3(HIDDEN / BN, N_SUBS / BM, 1), 256, 0, stream>>>(
        sp, sub_W1, nullptr, wh_s, N_SUBS, HIDDEN, HIDDEN, HIDDEN,
        sub_asrc1, sub_adst1, fs_s, fd_s);
    // 10. sub GAT aggregate -> final output
    gat_agg<<<N_SUBS, 512, 0, stream>>>(wh_s, fs_s, fd_s, cnt_s, nbr_s,
                                        out, N_SUBS);
}

// Round 5
// 231.543 us; speedup vs baseline: 1.3825x; 1.1045x over previous
//
#include <hip/hip_runtime.h>
#include <hip/hip_bf16.h>
#include <math.h>

// Problem constants (fixed by reference)
#define N_NODES 4096
#define N_SUBS  1024
#define NFEAT   128
#define HIDDEN  512
#define NHEADS  8
#define DHEAD   64
#define CAP     128   // max neighbors/row (mean ~42, sd ~6.4; 128 = +13 sigma)
#define ROWG    4     // neighbor groups in gat_agg phase B

// ---------------------------------------------------------------------------
// Ballot-based edge extraction: one WAVE per row, no atomics, ascending order.
// ---------------------------------------------------------------------------
__global__ __launch_bounds__(256) void extract_ballot(const float* __restrict__ adj,
                                                      int N,
                                                      int* __restrict__ cnt,
                                                      int* __restrict__ nbr) {
    const int w = threadIdx.x >> 6;
    const int lane = threadIdx.x & 63;
    const int row = blockIdx.x * 4 + w;
    const float4* rowp = (const float4*)(adj + (size_t)row * N);
    int* nrow = nbr + (row << 7);
    const int n4 = N >> 2;
    int c = 0;
    const unsigned long long below = (1ull << lane) - 1ull;
    for (int c4 = lane; c4 < n4; c4 += 64) {
        const float4 v = rowp[c4];
        const int col = c4 << 2;
        unsigned long long m;
        bool p;
        p = v.x > 0.0f; m = __ballot(p);
        if (p) { int q = c + __popcll(m & below); if (q < CAP) nrow[q] = col; }
        c += __popcll(m);
        p = v.y > 0.0f; m = __ballot(p);
        if (p) { int q = c + __popcll(m & below); if (q < CAP) nrow[q] = col + 1; }
        c += __popcll(m);
        p = v.z > 0.0f; m = __ballot(p);
        if (p) { int q = c + __popcll(m & below); if (q < CAP) nrow[q] = col + 2; }
        c += __popcll(m);
        p = v.w > 0.0f; m = __ballot(p);
        if (p) { int q = c + __popcll(m & below); if (q < CAP) nrow[q] = col + 3; }
        c += __popcll(m);
    }
    if (lane == 0) cnt[row] = c < CAP ? c : CAP;
}

// ---------------------------------------------------------------------------
// fp32 tiled GEMM: C[M,N]=A[M,K]@B[K,N](+bias). BM=BN=64, BK=16, 4x4/thread.
// blockIdx.z = K-chunk (split-K partials at C + z*M*N).
// Optional fused attention-logit epilogue (asrc != nullptr): BN==DHEAD==64 so
// head h == blockIdx.x. Requires gridDim.z == 1 when asrc != nullptr.
// ---------------------------------------------------------------------------
#define BM 64
#define BN 64
#define BK 16
__global__ __launch_bounds__(256) void gemm_f32(const float* __restrict__ A,
                                                const float* __restrict__ B,
                                                const float* __restrict__ bias,
                                                float* __restrict__ C,
                                                int M, int N, int K, int k_chunk,
                                                const float* __restrict__ asrc,
                                                const float* __restrict__ adst,
                                                float* __restrict__ fs,
                                                float* __restrict__ fd) {
    __shared__ float As[BK][BM + 4];
    __shared__ float Bs[BK][BN + 4];
    const int tid = threadIdx.x;
    const int bm = blockIdx.y * BM;
    const int bn = blockIdx.x * BN;
    const int k_start = blockIdx.z * k_chunk;
    const int k_end = (k_start + k_chunk) < K ? (k_start + k_chunk) : K;
    float* Cw = C + (size_t)blockIdx.z * M * N;
    const int tr = tid >> 4;
    const int tc = tid & 15;
    const int am = tid >> 2;
    const int ak4 = (tid & 3) * 4;
    const int bk = tid >> 4;
    const int bn0 = (tid & 15) * 4;
    float acc[4][4] = {};
    for (int k0 = k_start; k0 < k_end; k0 += BK) {
        const float4 va = *(const float4*)&A[(size_t)(bm + am) * K + k0 + ak4];
        const float4 vb = *(const float4*)&B[(size_t)(k0 + bk) * N + bn + bn0];
        As[ak4 + 0][am] = va.x;
        As[ak4 + 1][am] = va.y;
        As[ak4 + 2][am] = va.z;
        As[ak4 + 3][am] = va.w;
        *(float4*)&Bs[bk][bn0] = vb;
        __syncthreads();
#pragma unroll
        for (int k = 0; k < BK; k++) {
            const float4 a4 = *(const float4*)&As[k][tr * 4];
            const float4 b4 = *(const float4*)&Bs[k][tc * 4];
            const float a[4] = {a4.x, a4.y, a4.z, a4.w};
            const float b[4] = {b4.x, b4.y, b4.z, b4.w};
#pragma unroll
            for (int i = 0; i < 4; i++)
#pragma unroll
                for (int j = 0; j < 4; j++)
                    acc[i][j] += a[i] * b[j];
        }
        __syncthreads();
    }
#pragma unroll
    for (int i = 0; i < 4; i++) {
        const int m = bm + tr * 4 + i;
        if (bias) {
            const float4 bv = *(const float4*)&bias[bn + tc * 4];
            acc[i][0] += bv.x; acc[i][1] += bv.y; acc[i][2] += bv.z; acc[i][3] += bv.w;
        }
        float4 o = {acc[i][0], acc[i][1], acc[i][2], acc[i][3]};
        *(float4*)&Cw[(size_t)m * N + bn + tc * 4] = o;
    }
    if (asrc) {
        const int h = blockIdx.x;                  // BN==DHEAD
        const float4 as4 = *(const float4*)&asrc[h * DHEAD + tc * 4];
        const float4 ad4 = *(const float4*)&adst[h * DHEAD + tc * 4];
#pragma unroll
        for (int i = 0; i < 4; i++) {
            float vs = acc[i][0] * as4.x + acc[i][1] * as4.y +
                       acc[i][2] * as4.z + acc[i][3] * as4.w;
            float vd = acc[i][0] * ad4.x + acc[i][1] * ad4.y +
                       acc[i][2] * ad4.z + acc[i][3] * ad4.w;
#pragma unroll
            for (int off = 1; off < 16; off <<= 1) {
                vs += __shfl_xor(vs, off, 64);
                vd += __shfl_xor(vd, off, 64);
            }
            if (tc == 0) {
                const int m = bm + tr * 4 + i;
                fs[h * M + m] = vs;
                fd[h * M + m] = vd;
            }
        }
    }
}

// Sum split-K partials: outp[i] = sum_z part[z*len + i]
__global__ __launch_bounds__(256) void reduce_partials(const float* __restrict__ part,
                                                       float* __restrict__ outp,
                                                       int len, int nz) {
    int i = blockIdx.x * 256 + threadIdx.x;
    if (i < len) {
        float s = 0.0f;
        for (int z = 0; z < nz; z++) s += part[(size_t)z * len + i];
        outp[i] = s;
    }
}

// bias partials: part[z*HIDDEN+n] = sum_{k in chunk z} lin_b[k]*W1[k,n]
__global__ __launch_bounds__(256) void gemv_bias_part(const float* __restrict__ lin_b,
                                                      const float* __restrict__ W1,
                                                      float* __restrict__ part) {
    const int n = blockIdx.x * 256 + threadIdx.x;    // 0..511
    const int z = blockIdx.y;                        // 0..15
    const int k0 = z * (HIDDEN / 16);
    float s = 0.0f;
#pragma unroll 4
    for (int k = k0; k < k0 + HIDDEN / 16; k++)
        s += lin_b[k] * W1[(size_t)k * HIDDEN + n];
    part[z * HIDDEN + n] = s;
}

// ---------------------------------------------------------------------------
// Fused split-K reduce + attention logits for the sub layer.
// Grid = M rows, 512 threads. Thread owns one hidden element.
// ---------------------------------------------------------------------------
__global__ __launch_bounds__(512) void reduce_fsfd(const float* __restrict__ part,
                                                   float* __restrict__ wh,
                                                   const float* __restrict__ asrc,
                                                   const float* __restrict__ adst,
                                                   float* __restrict__ fs,
                                                   float* __restrict__ fd,
                                                   int M, int nz) {
    const int n = blockIdx.x;
    const int tid = threadIdx.x;
    float v = 0.0f;
    for (int z = 0; z < nz; z++)
        v += part[((size_t)z * M + n) * HIDDEN + tid];
    wh[(size_t)n * HIDDEN + tid] = v;
    const int h = tid >> 6;
    const int d = tid & 63;
    float vs = v * asrc[h * DHEAD + d];
    float vd = v * adst[h * DHEAD + d];
#pragma unroll
    for (int off = 32; off >= 1; off >>= 1) {
        vs += __shfl_xor(vs, off, 64);
        vd += __shfl_xor(vd, off, 64);
    }
    if (d == 0) {
        fs[h * M + n] = vs;
        fd[h * M + n] = vd;
    }
}

// ---------------------------------------------------------------------------
// GAT aggregate v2. Phase A: per-head softmax (wave h, lanes over neighbors),
// weights normalized in place. Phase B: float4 gather — 128 threads cover one
// 512-float row, 4 neighbor groups in flight, x2 unrolled; LDS reduce.
// ---------------------------------------------------------------------------
__global__ __launch_bounds__(512) void gat_agg(const float* __restrict__ Wh,
                                               const float* __restrict__ fs,
                                               const float* __restrict__ fd,
                                               const int* __restrict__ cnt,
                                               const int* __restrict__ nbr,
                                               float* __restrict__ out, int N) {
    __shared__ int snbr[CAP];
    __shared__ float ex[NHEADS][CAP + 1];
    __shared__ float sacc[ROWG][HIDDEN];
    const int i = blockIdx.x;
    const int tid = threadIdx.x;
    int C = cnt[i];
    C = C < CAP ? C : CAP;
    for (int k = tid; k < C; k += 512) snbr[k] = nbr[(i << 7) + k];
    __syncthreads();
    {
        const int h = tid >> 6;
        const int lane = tid & 63;
        const float fsi = fs[h * N + i];
        const float* __restrict__ fdh = fd + h * N;
        float m = -1e30f;
        for (int k = lane; k < C; k += 64) {
            float e = fsi + fdh[snbr[k]];
            e = e > 0.0f ? e : 0.2f * e;
            ex[h][k] = e;
            m = fmaxf(m, e);
        }
#pragma unroll
        for (int off = 32; off >= 1; off >>= 1) m = fmaxf(m, __shfl_xor(m, off, 64));
        float ssum = 0.0f;
        for (int k = lane; k < C; k += 64) {
            float v = __expf(ex[h][k] - m);
            ex[h][k] = v;
            ssum += v;
        }
#pragma unroll
        for (int off = 32; off >= 1; off >>= 1) ssum += __shfl_xor(ssum, off, 64);
        const float inv = 1.0f / ssum;
        for (int k = lane; k < C; k += 64) ex[h][k] *= inv;
    }
    __syncthreads();
    const int g = tid >> 7;
    const int t = tid & 127;
    const int hh = t >> 4;
    float4 acc = {0.f, 0.f, 0.f, 0.f};
    int k = g;
    for (; k + ROWG < C; k += 2 * ROWG) {
        const int j0 = snbr[k];
        const int j1 = snbr[k + ROWG];
        const float a0 = ex[hh][k];
        const float a1 = ex[hh][k + ROWG];
        const float4 w0 = *(const float4*)&Wh[(size_t)j0 * HIDDEN + 4 * t];
        const float4 w1 = *(const float4*)&Wh[(size_t)j1 * HIDDEN + 4 * t];
        acc.x += a0 * w0.x + a1 * w1.x;
        acc.y += a0 * w0.y + a1 * w1.y;
        acc.z += a0 * w0.z + a1 * w1.z;
        acc.w += a0 * w0.w + a1 * w1.w;
    }
    if (k < C) {
        const int j0 = snbr[k];
        const float a0 = ex[hh][k];
        const float4 w0 = *(const float4*)&Wh[(size_t)j0 * HIDDEN + 4 * t];
        acc.x += a0 * w0.x; acc.y += a0 * w0.y;
        acc.z += a0 * w0.z; acc.w += a0 * w0.w;
    }
    *(float4*)&sacc[g][4 * t] = acc;
    __syncthreads();
    if (g == 0) {
        float4 r = acc;
#pragma unroll
        for (int gg = 1; gg < ROWG; gg++) {
            const float4 o = *(const float4*)&sacc[gg][4 * t];
            r.x += o.x; r.y += o.y; r.z += o.z; r.w += o.w;
        }
        r.x = r.x > 0.0f ? r.x : __expf(r.x) - 1.0f;
        r.y = r.y > 0.0f ? r.y : __expf(r.y) - 1.0f;
        r.z = r.z > 0.0f ? r.z : __expf(r.z) - 1.0f;
        r.w = r.w > 0.0f ? r.w : __expf(r.w) - 1.0f;
        *(float4*)&out[(size_t)i * HIDDEN + 4 * t] = r;
    }
}

// ---------------------------------------------------------------------------
// Segment-mean pooling. seg_ids sorted. One block per substation.
// ---------------------------------------------------------------------------
__global__ __launch_bounds__(512) void pool_kernel(const float* __restrict__ hin,
                                                   const int* __restrict__ seg,
                                                   float* __restrict__ sout) {
    const int s = blockIdx.x;
    const int d = threadIdx.x;
    int lo = 0, hi = N_NODES;
    while (lo < hi) { int mid = (lo + hi) >> 1; if (seg[mid] < s) lo = mid + 1; else hi = mid; }
    const int start = lo;
    hi = N_NODES;
    while (lo < hi) { int mid = (lo + hi) >> 1; if (seg[mid] < s + 1) lo = mid + 1; else hi = mid; }
    const int end = lo;
    float acc = 0.0f;
    for (int r = start; r < end; r++) acc += hin[(size_t)r * HIDDEN + d];
    const int c = end - start;
    sout[(size_t)s * HIDDEN + d] = acc / (c > 0 ? (float)c : 1.0f);
}

// ---------------------------------------------------------------------------
extern "C" void kernel_launch(void* const* d_in, const int* in_sizes, int n_in,
                              void* d_out, int out_size, void* d_ws, size_t ws_size,
                              hipStream_t stream) {
    const float* x        = (const float*)d_in[0];
    const float* adj_node = (const float*)d_in[1];
    const float* adj_sub  = (const float*)d_in[2];
    const int*   seg_ids  = (const int*)d_in[3];
    const float* lin_w    = (const float*)d_in[4];
    const float* lin_b    = (const float*)d_in[5];
    // _stacked_gats bug: every layer reads the ORIGINAL h; only the LAST
    // layer's output survives. Use layer index 1 only.
    const float* node_W1    = (const float*)d_in[6]  + HIDDEN * HIDDEN;
    const float* node_asrc1 = (const float*)d_in[7]  + NHEADS * DHEAD;
    const float* node_adst1 = (const float*)d_in[8]  + NHEADS * DHEAD;
    const float* sub_W1     = (const float*)d_in[9]  + HIDDEN * HIDDEN;
    const float* sub_asrc1  = (const float*)d_in[10] + NHEADS * DHEAD;
    const float* sub_adst1  = (const float*)d_in[11] + NHEADS * DHEAD;
    float* out = (float*)d_out;

    char* ws = (char*)d_ws;
    float* bufA  = (float*)(ws);                              // 8 MB
    float* bufB  = (float*)(ws + (size_t)8 * 1024 * 1024);    // 8 MB
    float* fs_n  = (float*)(ws + (size_t)16 * 1024 * 1024);
    float* fd_n  = fs_n + NHEADS * N_NODES;
    float* fs_s  = fd_n + NHEADS * N_NODES;
    float* fd_s  = fs_s + NHEADS * N_SUBS;
    int*   cnt_n = (int*)(fd_s + NHEADS * N_SUBS);
    int*   cnt_s = cnt_n + N_NODES;
    int*   nbr_n = cnt_s + N_SUBS;                            // 2 MB
    int*   nbr_s = nbr_n + N_NODES * CAP;                     // 512 KB

    // Phase-1 overlays in bufB (all consumed before gat_agg writes gatom):
    float* Wpart = bufB;                                      // 16*128*512 (4 MB)
    float* Wfuse = bufB + 16 * NFEAT * HIDDEN;                // 256 KB
    float* bpart = Wfuse + NFEAT * HIDDEN;                    // 16*512 (32 KB)
    float* bias2 = bpart + 16 * HIDDEN;                       // 2 KB
    float* wh_n  = bufA;                                      // 4096*512
    float* gatom = bufB;                                      // 4096*512 (phase 2)
    float* sp    = bufA;                                      // 1024*512 (wh_n dead)
    float* Spart = bufB;                                      // 4*1024*512 (gatom dead)
    float* wh_s  = bufA + (size_t)N_SUBS * HIDDEN;            // 1024*512

    // 1-2. edge extraction (ballot, no atomics)
    extract_ballot<<<N_NODES / 4, 256, 0, stream>>>(adj_node, N_NODES, cnt_n, nbr_n);
    extract_ballot<<<N_SUBS / 4, 256, 0, stream>>>(adj_sub, N_SUBS, cnt_s, nbr_s);
    // 3. Wfuse partials = lin_w @ node_W1 (split-K=16 -> 256 blocks)
    gemm_f32<<<dim3(HIDDEN / BN, NFEAT / BM, 16), 256, 0, stream>>>(
        lin_w, node_W1, nullptr, Wpart, NFEAT, HIDDEN, HIDDEN, HIDDEN / 16,
        nullptr, nullptr, nullptr, nullptr);
    // 4. bias partials = lin_b @ node_W1 (split-K=16)
    gemv_bias_part<<<dim3(HIDDEN / 256, 16), 256, 0, stream>>>(lin_b, node_W1, bpart);
    // 5. reduce Wfuse partials
    reduce_partials<<<NFEAT * HIDDEN / 256, 256, 0, stream>>>(
        Wpart, Wfuse, NFEAT * HIDDEN, 16);
    // 6. reduce bias partials
    reduce_partials<<<HIDDEN / 256, 256, 0, stream>>>(bpart, bias2, HIDDEN, 16);
    // 7. wh_n = x @ Wfuse + bias2, fused fs/fd epilogue (512 blocks)
    gemm_f32<<<dim3(HIDDEN / BN, N_NODES / BM, 1), 256, 0, stream>>>(
        x, Wfuse, bias2, wh_n, N_NODES, HIDDEN, NFEAT, NFEAT,
        node_asrc1, node_adst1, fs_n, fd_n);
    // 8. node GAT aggregate -> gatom
    gat_agg<<<N_NODES, 512, 0, stream>>>(wh_n, fs_n, fd_n, cnt_n, nbr_n,
                                         gatom, N_NODES);
    // 9. segment-mean pool -> sp
    pool_kernel<<<N_SUBS, 512, 0, stream>>>(gatom, seg_ids, sp);
    // 10. wh_s partials = sp @ sub_W1 (split-K=4 -> 512 blocks)
    gemm_f32<<<dim3(HIDDEN / BN, N_SUBS / BM, 4), 256, 0, stream>>>(
        sp, sub_W1, nullptr, Spart, N_SUBS, HIDDEN, HIDDEN, HIDDEN / 4,
        nullptr, nullptr, nullptr, nullptr);
    // 11. fused reduce + sub attention logits
    reduce_fsfd<<<N_SUBS, 512, 0, stream>>>(Spart, wh_s, sub_asrc1, sub_adst1,
                                            fs_s, fd_s, N_SUBS, 4);
    // 12. sub GAT aggregate -> final output
    gat_agg<<<N_SUBS, 512, 0, stream>>>(wh_s, fs_s, fd_s, cnt_s, nbr_s,
                                        out, N_SUBS);
}